// Round 7
// baseline (3899.468 us; speedup 1.0000x reference)
//
#include <hip/hip_runtime.h>
#include <cmath>

// LAGCNII round 9 (= round 8 hardened, resubmit after container failure):
//  (a) lin: REVERTED to the round-0 LDS-staged kernel — best measured variant
//      (105us vs 121 LDS-free vs 130 col-split).
//  (b) layer_fused: edge-parallel gather. One WAVE per edge (64 lanes x 4 f32 =
//      512B row), contiguous chunk per wave, unroll x4 -> 4 independent h-loads
//      in flight; accumulate into f32 LDS tile via ds_add_f32 (bank-rotated).
//      Row-recovery scan over LDS-staged rowp now EXPLICITLY BOUNDED (r<31)
//      so no state can produce an unbounded loop / watchdog kill.
//      Then in-place f32->bf16 convert and the barrier-free MFMA phase
//      (wave tile 32x32, W direct from L2).
// ws: h0|h|x bf16 (153.6MB) + bf16 W^T (1.2MB) + CSR ints (~2.4MB).

#define N_NODES 100000
#define N_EDGES 300000
#define DIN 256
#define CHN 256
#define DHID 128
#define NCLASS 40
#define NLAYER 8
#define SCAN_NB 98  // ceil(100000 / 1024)

typedef short bf16x8 __attribute__((ext_vector_type(8)));
typedef float f32x4 __attribute__((ext_vector_type(4)));

__device__ inline short f2bf(float f) {
  unsigned u = __float_as_uint(f);
  unsigned r = (u + 0x7FFFu + ((u >> 16) & 1u)) >> 16;
  return (short)r;
}
__device__ inline float bf2f(short s) {
  return __uint_as_float(((unsigned)(unsigned short)s) << 16);
}

// ---------------- CSR build (by dst) ----------------
__global__ void hist_kernel(const int* __restrict__ dst, int* __restrict__ cnt) {
  int e = blockIdx.x * 256 + threadIdx.x;
  if (e < N_EDGES) atomicAdd(&cnt[dst[e]], 1);
}

// per-block exclusive scan of 1024 values (256 thr x 4), block totals to bsums
__global__ __launch_bounds__(256) void bscan1(const int* __restrict__ cnt,
                                              int* __restrict__ rowp,
                                              int* __restrict__ bsums) {
  int tid = threadIdx.x;
  int base = blockIdx.x * 1024 + tid * 4;
  int v0 = 0, v1 = 0, v2 = 0, v3 = 0;
  if (base + 3 < N_NODES) {
    int4 v = *(const int4*)(cnt + base);
    v0 = v.x; v1 = v.y; v2 = v.z; v3 = v.w;
  } else {
    if (base + 0 < N_NODES) v0 = cnt[base + 0];
    if (base + 1 < N_NODES) v1 = cnt[base + 1];
    if (base + 2 < N_NODES) v2 = cnt[base + 2];
    if (base + 3 < N_NODES) v3 = cnt[base + 3];
  }
  int t = v0 + v1 + v2 + v3;
  int lane = tid & 63;
  int incl = t;
#pragma unroll
  for (int off = 1; off < 64; off <<= 1) {
    int x = __shfl_up(incl, off, 64);
    if (lane >= off) incl += x;
  }
  __shared__ int wsum[4];
  int wave = tid >> 6;
  if (lane == 63) wsum[wave] = incl;
  __syncthreads();
  int woff = 0;
  for (int w = 0; w < wave; w++) woff += wsum[w];
  int excl = woff + incl - t;
  int e0 = excl, e1 = e0 + v0, e2 = e1 + v1, e3 = e2 + v2;
  if (base + 0 < N_NODES) rowp[base + 0] = e0;
  if (base + 1 < N_NODES) rowp[base + 1] = e1;
  if (base + 2 < N_NODES) rowp[base + 2] = e2;
  if (base + 3 < N_NODES) rowp[base + 3] = e3;
  if (tid == 255) bsums[blockIdx.x] = woff + incl;
}

__global__ void bscan2(int* __restrict__ bsums, int* __restrict__ rowp) {
  if (threadIdx.x == 0 && blockIdx.x == 0) {
    int s = 0;
    for (int i = 0; i < SCAN_NB; i++) {
      int v = bsums[i];
      bsums[i] = s;
      s += v;
    }
    rowp[N_NODES] = s;
  }
}

__global__ __launch_bounds__(256) void bscan3(int* __restrict__ rowp,
                                              int* __restrict__ fill,
                                              const int* __restrict__ bsums) {
  int base = blockIdx.x * 1024 + threadIdx.x * 4;
  int off = bsums[blockIdx.x];
#pragma unroll
  for (int j = 0; j < 4; j++) {
    int i = base + j;
    if (i < N_NODES) {
      int p = rowp[i] + off;
      rowp[i] = p;
      fill[i] = p;
    }
  }
}

__global__ void scatter_kernel(const int* __restrict__ src, const int* __restrict__ dst,
                               int* __restrict__ fill, int* __restrict__ col) {
  int e = blockIdx.x * 256 + threadIdx.x;
  if (e < N_EDGES) {
    int p = atomicAdd(&fill[dst[e]], 1);
    col[p] = src[e];
  }
}

// ---------------- weight prep: bf16 transposed weights ----------------
__global__ void prep_w_kernel(const float* __restrict__ lw, const float* __restrict__ gw,
                              short* __restrict__ linT, short* __restrict__ gcnT) {
  int i = blockIdx.x * 256 + threadIdx.x;
  if (i < 2 * 128 * 256) {
    int v = i >> 15;
    int rem = i & 32767;
    int n = rem >> 8;
    int k = rem & 255;
    linT[i] = f2bf(lw[v * (DIN * DHID) + k * DHID + n]);
  }
  int j = i - 2 * 128 * 256;
  if (j >= 0 && j < 8 * 256 * 256) {
    int l = j >> 16;
    int rem = j & 65535;
    int n = rem >> 8;
    int k = rem & 255;
    gcnT[j] = f2bf(gw[l * (CHN * CHN) + k * CHN + n]);
  }
}

// ---------------- lin: h0[:, v*128+n] = relu(Xv @ Wv + bv), bf16 out ----------------
// Round-0 LDS-staged version: best measured (105us).
__global__ __launch_bounds__(256) void lin_mfma_kernel(const float* __restrict__ x0,
                                                       const float* __restrict__ x1,
                                                       const short* __restrict__ linT,
                                                       const float* __restrict__ lb,
                                                       short* __restrict__ h0) {
  const int view = blockIdx.y;
  const float* __restrict__ X = view ? x1 : x0;
  const short* __restrict__ Wt = linT + view * (DHID * DIN);  // [n][k]
  const int row0 = blockIdx.x * 128;
  __shared__ short As[128 * 40];
  __shared__ short Bs[128 * 40];
  const int tid = threadIdx.x;
  const int lane = tid & 63, wave = tid >> 6;
  const int quad = lane >> 4, mrem = lane & 15;
  const int wrow = (wave & 1) * 64, wcol = (wave >> 1) * 64;

  f32x4 acc[4][4];
#pragma unroll
  for (int i = 0; i < 4; i++)
#pragma unroll
    for (int j = 0; j < 4; j++) acc[i][j] = (f32x4){0.f, 0.f, 0.f, 0.f};

  const int sr = tid >> 1;
  const int sk = (tid & 1) * 16;
  for (int k0 = 0; k0 < DIN; k0 += 32) {
    {
      int gr = row0 + sr;
      float v[16];
      if (gr < N_NODES) {
        const float* p = X + (size_t)gr * DIN + k0 + sk;
        *(float4*)(v + 0) = *(const float4*)(p + 0);
        *(float4*)(v + 4) = *(const float4*)(p + 4);
        *(float4*)(v + 8) = *(const float4*)(p + 8);
        *(float4*)(v + 12) = *(const float4*)(p + 12);
      } else {
#pragma unroll
        for (int i = 0; i < 16; i++) v[i] = 0.f;
      }
      short s[16];
#pragma unroll
      for (int i = 0; i < 16; i++) s[i] = f2bf(v[i]);
      *(bf16x8*)&As[sr * 40 + sk] = *(bf16x8*)(s);
      *(bf16x8*)&As[sr * 40 + sk + 8] = *(bf16x8*)(s + 8);
    }
    {
      const short* p = Wt + (size_t)sr * DIN + k0 + sk;
      bf16x8 b0 = *(const bf16x8*)p;
      bf16x8 b1 = *(const bf16x8*)(p + 8);
      *(bf16x8*)&Bs[sr * 40 + sk] = b0;
      *(bf16x8*)&Bs[sr * 40 + sk + 8] = b1;
    }
    __syncthreads();
    bf16x8 af[4], bfr[4];
#pragma unroll
    for (int i = 0; i < 4; i++) af[i] = *(const bf16x8*)&As[(wrow + i * 16 + mrem) * 40 + quad * 8];
#pragma unroll
    for (int j = 0; j < 4; j++) bfr[j] = *(const bf16x8*)&Bs[(wcol + j * 16 + mrem) * 40 + quad * 8];
#pragma unroll
    for (int i = 0; i < 4; i++)
#pragma unroll
      for (int j = 0; j < 4; j++)
        acc[i][j] = __builtin_amdgcn_mfma_f32_16x16x32_bf16(af[i], bfr[j], acc[i][j], 0, 0, 0);
    __syncthreads();
  }
#pragma unroll
  for (int i = 0; i < 4; i++) {
#pragma unroll
    for (int j = 0; j < 4; j++) {
      int lcol = wcol + j * 16 + mrem;
      float bb = lb[view * DHID + lcol];
#pragma unroll
      for (int r = 0; r < 4; r++) {
        int grow = row0 + wrow + i * 16 + quad * 4 + r;
        if (grow < N_NODES)
          h0[(size_t)grow * CHN + view * DHID + lcol] = f2bf(fmaxf(acc[i][j][r] + bb, 0.f));
      }
    }
  }
}

// ---------------- fused layer: agg + residual + GEMM + identity map + relu --------
// 512 threads, tile = 32 rows x 256 cols. LDS: f32 accum tile [32][264] (33.8KB),
// reused in-place as bf16 As for the GEMM. Grid 3125*32 == N exactly.
// Gather: ONE WAVE PER EDGE (64 lanes x 4 f32 = full 512B row), contiguous chunk
// per wave, unroll x4 (4 independent loads in flight), ds f32 atomicAdd with
// bank-rotated issue order. Row scan over LDS rowp slice is bounded (r<31).
__global__ __launch_bounds__(512, 8) void layer_fused(const short* __restrict__ h,
                                                      const short* __restrict__ h0,
                                                      const int* __restrict__ rowp,
                                                      const int* __restrict__ col,
                                                      const short* __restrict__ Wt,  // [n][k]
                                                      short* __restrict__ out, float beta) {
  __shared__ float xf[32 * 264];  // 33.8 KB; later aliased as bf16 As
  __shared__ int rps[33];
  const int tid = threadIdx.x;
  const int row0 = blockIdx.x * 32;

  // ---- init: xf = (ALPHA/(1-ALPHA)) * h0 = h0/9 ; stage rowp slice ----
  const int ir = tid >> 4;         // 0..31
  const int ic = (tid & 15) * 16;  // 16 f32 per thread
  {
    const int gr = row0 + ir;
    float t[16];
    if (gr < N_NODES) {
      bf16x8 a = *(const bf16x8*)(h0 + (size_t)gr * CHN + ic);
      bf16x8 b = *(const bf16x8*)(h0 + (size_t)gr * CHN + ic + 8);
#pragma unroll
      for (int q = 0; q < 8; q++) {
        t[q] = 0.11111111f * bf2f(a[q]);
        t[q + 8] = 0.11111111f * bf2f(b[q]);
      }
    } else {
#pragma unroll
      for (int q = 0; q < 16; q++) t[q] = 0.f;
    }
#pragma unroll
    for (int q = 0; q < 4; q++) *(f32x4*)&xf[ir * 264 + ic + q * 4] = *(const f32x4*)&t[q * 4];
  }
  if (tid <= 32) rps[tid] = rowp[min(row0 + tid, N_NODES)];
  __syncthreads();

  // ---- edge-parallel gather ----
  {
    const int wv = tid >> 6, ln = tid & 63;
    const int eb = rps[0], ee = rps[32];
    const int ne = ee - eb;
    const int chunk = (ne + 7) >> 3;
    const int pb = eb + wv * chunk;
    const int pe = min(pb + chunk, ee);
    const int rot = (ln >> 3) & 3;
    int r = 0;
    if (pb < pe) {
      while (r < 31 && pb >= rps[r + 1]) ++r;
      for (int p = pb; p < pe; p += 4) {
        const int n4 = min(4, pe - p);
        int s0 = col[p];
        int s1 = (n4 > 1) ? col[p + 1] : -1;
        int s2 = (n4 > 2) ? col[p + 2] : -1;
        int s3 = (n4 > 3) ? col[p + 3] : -1;
        short4 v0, v1, v2, v3;
        v0 = *(const short4*)(h + (size_t)s0 * CHN + ln * 4);
        v1 = (s1 >= 0) ? *(const short4*)(h + (size_t)s1 * CHN + ln * 4) : make_short4(0, 0, 0, 0);
        v2 = (s2 >= 0) ? *(const short4*)(h + (size_t)s2 * CHN + ln * 4) : make_short4(0, 0, 0, 0);
        v3 = (s3 >= 0) ? *(const short4*)(h + (size_t)s3 * CHN + ln * 4) : make_short4(0, 0, 0, 0);
#pragma unroll
        for (int u = 0; u < 4; ++u) {
          if (u < n4) {
            short4 v = (u == 0) ? v0 : (u == 1) ? v1 : (u == 2) ? v2 : v3;
            while (r < 31 && p + u >= rps[r + 1]) ++r;
            const float f0 = bf2f(v.x), f1 = bf2f(v.y), f2 = bf2f(v.z), f3 = bf2f(v.w);
            float* xr = &xf[r * 264 + ln * 4];
#pragma unroll
            for (int t2 = 0; t2 < 4; ++t2) {
              const int q = (t2 + rot) & 3;
              const float val = (q == 0) ? f0 : (q == 1) ? f1 : (q == 2) ? f2 : f3;
              atomicAdd(&xr[q], val);
            }
          }
        }
      }
    }
  }
  __syncthreads();

  // ---- in-place convert: As(bf16) = f2bf(0.9 * xf) ----
  short* As = (short*)xf;
  {
    short o[16];
#pragma unroll
    for (int q = 0; q < 4; q++) {
      f32x4 tv = *(const f32x4*)&xf[ir * 264 + ic + q * 4];
      o[q * 4 + 0] = f2bf(0.9f * tv[0]);
      o[q * 4 + 1] = f2bf(0.9f * tv[1]);
      o[q * 4 + 2] = f2bf(0.9f * tv[2]);
      o[q * 4 + 3] = f2bf(0.9f * tv[3]);
    }
    __syncthreads();
#pragma unroll
    for (int q = 0; q < 2; q++) *(bf16x8*)&As[ir * 264 + ic + q * 8] = *(const bf16x8*)&o[q * 8];
  }
  __syncthreads();

  // ---- barrier-free GEMM; wave tile 32 rows x 32 cols; B direct from L2 ----
  const int lane = tid & 63, wave = tid >> 6;
  const int quad = lane >> 4, mrem = lane & 15;
  const int wcol = wave * 32;  // 8 waves x 32 = 256 cols
  f32x4 acc2[2][2];
#pragma unroll
  for (int i = 0; i < 2; i++)
#pragma unroll
    for (int j = 0; j < 2; j++) acc2[i][j] = (f32x4){0.f, 0.f, 0.f, 0.f};

#pragma unroll
  for (int k0 = 0; k0 < CHN; k0 += 32) {
    bf16x8 af[2], bfr[2];
#pragma unroll
    for (int j = 0; j < 2; j++)
      bfr[j] = *(const bf16x8*)(Wt + (size_t)(wcol + j * 16 + mrem) * CHN + k0 + quad * 8);
#pragma unroll
    for (int i = 0; i < 2; i++)
      af[i] = *(const bf16x8*)&As[(i * 16 + mrem) * 264 + k0 + quad * 8];
#pragma unroll
    for (int i = 0; i < 2; i++)
#pragma unroll
      for (int j = 0; j < 2; j++)
        acc2[i][j] = __builtin_amdgcn_mfma_f32_16x16x32_bf16(af[i], bfr[j], acc2[i][j], 0, 0, 0);
  }

  // ---- Epilogue: residual from LDS (already bf16 x), write h ----
  const float omb = 1.f - beta;
#pragma unroll
  for (int i = 0; i < 2; i++) {
#pragma unroll
    for (int j = 0; j < 2; j++) {
      const int lcol = wcol + j * 16 + mrem;
#pragma unroll
      for (int r2 = 0; r2 < 4; r2++) {
        const int lrow = i * 16 + quad * 4 + r2;
        const int grow = row0 + lrow;
        if (grow < N_NODES) {
          float xv = bf2f(As[lrow * 264 + lcol]);
          out[(size_t)grow * CHN + lcol] = f2bf(fmaxf(omb * xv + beta * acc2[i][j][r2], 0.f));
        }
      }
    }
  }
}

// ---------------- out: out = h @ Wo + bo  (M=100000, K=256, N=40) ----------------
__global__ __launch_bounds__(256) void out_kernel(const short* __restrict__ h,
                                                  const float* __restrict__ W,
                                                  const float* __restrict__ b,
                                                  float* __restrict__ out) {
  __shared__ float xs[32][260];
  __shared__ float ws[64][40];
  const int row0 = blockIdx.x * 32;
  const int tid = threadIdx.x;
  for (int f = tid; f < 1024; f += 256) {
    int r = f >> 5;
    int c = (f & 31) * 8;
    bf16x8 v = *(const bf16x8*)(h + (size_t)(row0 + r) * CHN + c);
    float t0[8];
#pragma unroll
    for (int q = 0; q < 8; q++) t0[q] = bf2f(v[q]);
    *(float4*)&xs[r][c] = *(float4*)(t0);
    *(float4*)&xs[r][c + 4] = *(float4*)(t0 + 4);
  }
  const int r = tid >> 3;
  const int cg = (tid & 7) * 5;
  float acc[5];
#pragma unroll
  for (int j = 0; j < 5; j++) acc[j] = b[cg + j];
  for (int k0 = 0; k0 < CHN; k0 += 64) {
    for (int i = tid; i < 64 * 40; i += 256) {
      int k = i / 40, c = i % 40;
      ws[k][c] = W[(size_t)(k0 + k) * NCLASS + c];
    }
    __syncthreads();
#pragma unroll 8
    for (int k = 0; k < 64; k++) {
      float xv = xs[r][k0 + k];
#pragma unroll
      for (int j = 0; j < 5; j++) acc[j] += xv * ws[k][cg + j];
    }
    __syncthreads();
  }
  float* op = out + (size_t)(row0 + r) * NCLASS + cg;
#pragma unroll
  for (int j = 0; j < 5; j++) op[j] = acc[j];
}

extern "C" void kernel_launch(void* const* d_in, const int* in_sizes, int n_in,
                              void* d_out, int out_size, void* d_ws, size_t ws_size,
                              hipStream_t stream) {
  const float* x0 = (const float*)d_in[0];
  const float* x1 = (const float*)d_in[1];
  const int* ei = (const int*)d_in[2];
  const float* lw = (const float*)d_in[3];
  const float* lb = (const float*)d_in[4];
  const float* gw = (const float*)d_in[5];
  const float* ow = (const float*)d_in[6];
  const float* ob = (const float*)d_in[7];
  float* outp = (float*)d_out;

  const size_t NC = (size_t)N_NODES * CHN;
  short* h0 = (short*)d_ws;
  short* hb = h0 + NC;
  short* xb = hb + NC;
  short* linT = xb + NC;                    // 153.6MB offset, 16B aligned
  short* gcnT = linT + 2 * DHID * DIN;      // +128KB
  int* cnt = (int*)(gcnT + 8 * CHN * CHN);  // +1MB
  int* rowp = cnt + N_NODES;
  int* fill = rowp + N_NODES + 1;
  int* col = fill + N_NODES;
  int* bsums = col + N_EDGES;

  const int* src = ei;
  const int* dst = ei + N_EDGES;

  hipMemsetAsync(cnt, 0, N_NODES * sizeof(int), stream);
  hist_kernel<<<(N_EDGES + 255) / 256, 256, 0, stream>>>(dst, cnt);
  bscan1<<<SCAN_NB, 256, 0, stream>>>(cnt, rowp, bsums);
  bscan2<<<1, 64, 0, stream>>>(bsums, rowp);
  bscan3<<<SCAN_NB, 256, 0, stream>>>(rowp, fill, bsums);
  scatter_kernel<<<(N_EDGES + 255) / 256, 256, 0, stream>>>(src, dst, fill, col);
  prep_w_kernel<<<(2 * 128 * 256 + 8 * 256 * 256 + 255) / 256, 256, 0, stream>>>(lw, gw, linT, gcnT);

  dim3 lg((N_NODES + 127) / 128, 2);
  lin_mfma_kernel<<<lg, 256, 0, stream>>>(x0, x1, linT, lb, h0);

  // layers: fused agg+gemm; h ping-pongs hb <-> xb (gather reads prev buffer,
  // kernel-launch boundary is the producer/consumer barrier)
  const short* hin = h0;
  for (int l = 0; l < NLAYER; ++l) {
    float beta = logf(0.5f / (float)(l + 1) + 1.0f);
    short* hout = (l & 1) ? xb : hb;
    layer_fused<<<(N_NODES + 31) / 32, 512, 0, stream>>>(hin, h0, rowp, col,
                                                         gcnT + (size_t)l * CHN * CHN,
                                                         hout, beta);
    hin = hout;
  }
  out_kernel<<<N_NODES / 32, 256, 0, stream>>>(hin, ow, ob, outp);
}